// Round 4
// baseline (413.932 us; speedup 1.0000x reference)
//
#include <hip/hip_runtime.h>
#include <stdint.h>

typedef unsigned short u16;
typedef __attribute__((ext_vector_type(8))) short short8;
typedef __attribute__((ext_vector_type(4))) float f32x4;

#define NB 2
#define NS 2048
#define ND 1024
#define NH 16
#define NDH 64
#define NBS (NB*NS)   // 4096 rows

__device__ __forceinline__ float bf2f(u16 u) {
  union { uint32_t i; float f; } c; c.i = ((uint32_t)u) << 16; return c.f;
}
__device__ __forceinline__ u16 f2bf(float f) {
  union { float f; uint32_t i; } c; c.f = f;
  uint32_t r = (c.i + 0x7fffu + ((c.i >> 16) & 1u)) >> 16;
  return (u16)r;
}

// ---------------- f32 -> bf16 elementwise ----------------
__global__ __launch_bounds__(256)
void k_f32_to_bf16(const float* __restrict__ X, u16* __restrict__ Y, int n4) {
  int i = blockIdx.x * 256 + threadIdx.x;
  if (i >= n4) return;
  float4 v = ((const float4*)X)[i];
  uint2 o;
  o.x = (uint32_t)f2bf(v.x) | ((uint32_t)f2bf(v.y) << 16);
  o.y = (uint32_t)f2bf(v.z) | ((uint32_t)f2bf(v.w) << 16);
  ((uint2*)Y)[i] = o;
}

// ---------------- transpose f32[K][N] -> bf16[N][K] ----------------
__global__ __launch_bounds__(256)
void k_transpose_bf16(const float* __restrict__ W, u16* __restrict__ WT, int K, int N) {
  __shared__ float tile[32][33];
  const int tx = threadIdx.x & 31, ty = threadIdx.x >> 5;
  const int n0 = blockIdx.x << 5, k0 = blockIdx.y << 5;
  #pragma unroll
  for (int j = 0; j < 4; ++j)
    tile[ty + 8*j][tx] = W[(size_t)(k0 + ty + 8*j) * N + (n0 + tx)];
  __syncthreads();
  #pragma unroll
  for (int j = 0; j < 4; ++j)
    WT[(size_t)(n0 + ty + 8*j) * K + (k0 + tx)] = f2bf(tile[tx][ty + 8*j]);
}

// ---------------- transpose V out of qkv: [z][dh] -> Vt[bh][dh][z] (bf16) ----------------
__global__ __launch_bounds__(256)
void k_vt(const u16* __restrict__ qkv, u16* __restrict__ Vt) {
  __shared__ u16 tile[64][72];
  const int zb = blockIdx.x;
  const int bh = blockIdx.y;
  const int b = bh >> 4, h = bh & 15;
  const int t = threadIdx.x;
  const int r = t >> 2, seg = (t & 3) * 16;
  const u16* src = qkv + ((size_t)(b * NS + zb * 64 + r)) * 3072 + 2048 + h * 64 + seg;
  *(short8*)(&tile[r][seg])     = *(const short8*)(src);
  *(short8*)(&tile[r][seg + 8]) = *(const short8*)(src + 8);
  __syncthreads();
  const int dh = t >> 2, zs = (t & 3) * 16;
  short8 o0, o1;
  #pragma unroll
  for (int i = 0; i < 8; ++i) o0[i] = (short)tile[zs + i][dh];
  #pragma unroll
  for (int i = 0; i < 8; ++i) o1[i] = (short)tile[zs + 8 + i][dh];
  u16* dst = Vt + (size_t)(bh * 64 + dh) * NS + zb * 64 + zs;
  *(short8*)(dst)     = o0;
  *(short8*)(dst + 8) = o1;
}

// ---------------- async global->LDS, 16B ----------------
__device__ __forceinline__ void gload_lds16(const void* g, void* l) {
  __builtin_amdgcn_global_load_lds(
      (const __attribute__((address_space(1))) void*)(void*)(uintptr_t)g,
      (__attribute__((address_space(3))) void*)l, 16, 0, 0);
}

// ---------------- 128x128 bf16 MFMA GEMM (m97 structure), split-K capable ----------------
// C[M][N] (+ z-chunk offset) = A[M][Kstride restricted to Klen] * BT^T (+ bias)
template<bool OUT_BF16, bool RELU>
__global__ __launch_bounds__(256)
void k_gemm_bt(const u16* __restrict__ A, const u16* __restrict__ BT,
               const float* __restrict__ bias, void* __restrict__ C,
               int M, int N, int Kstride, int Klen, size_t zCstride)
{
  __shared__ u16 As[128 * 64];
  __shared__ u16 Bs[128 * 64];
  const int t = threadIdx.x, wave = t >> 6, lane = t & 63;
  const int m0 = blockIdx.y * 128, n0 = blockIdx.x * 128;
  const int wr = wave >> 1, wc = wave & 1;
  const int koff = blockIdx.z * Klen;
  A  += koff;
  BT += koff;

  f32x4 acc[4][4] = {};

  int srow[4], scol[4];
  #pragma unroll
  for (int p = 0; p < 4; ++p) {
    int o = p * 4096 + wave * 1024 + lane * 16;
    int r = o >> 7;
    int cb = o & 127;
    srow[p] = r;
    scol[p] = (cb ^ ((r & 7) << 4)) >> 1;
  }

  const int nkt = Klen >> 6;
  for (int kt = 0; kt < nkt; ++kt) {
    const int k0 = kt << 6;
    #pragma unroll
    for (int p = 0; p < 4; ++p) {
      const u16* srcA = A  + (size_t)(m0 + srow[p]) * Kstride + k0 + scol[p];
      const u16* srcB = BT + (size_t)(n0 + srow[p]) * Kstride + k0 + scol[p];
      gload_lds16(srcA, (char*)As + p * 4096 + wave * 1024);
      gload_lds16(srcB, (char*)Bs + p * 4096 + wave * 1024);
    }
    asm volatile("s_waitcnt vmcnt(0)" ::: "memory");
    __syncthreads();

    #pragma unroll
    for (int kk = 0; kk < 2; ++kk) {
      const int cbase = kk * 64 + ((lane >> 4) << 4);
      short8 af[4], bf[4];
      #pragma unroll
      for (int mi = 0; mi < 4; ++mi) {
        int r = wr * 64 + mi * 16 + (lane & 15);
        af[mi] = *(const short8*)((const char*)As + r * 128 + (cbase ^ ((r & 7) << 4)));
      }
      #pragma unroll
      for (int nj = 0; nj < 4; ++nj) {
        int r = wc * 64 + nj * 16 + (lane & 15);
        bf[nj] = *(const short8*)((const char*)Bs + r * 128 + (cbase ^ ((r & 7) << 4)));
      }
      #pragma unroll
      for (int mi = 0; mi < 4; ++mi)
        #pragma unroll
        for (int nj = 0; nj < 4; ++nj)
          acc[mi][nj] = __builtin_amdgcn_mfma_f32_16x16x32_bf16(af[mi], bf[nj], acc[mi][nj], 0, 0, 0);
    }
    __syncthreads();
  }

  const int lr = (lane >> 4) << 2;
  const int lc = lane & 15;
  #pragma unroll
  for (int nj = 0; nj < 4; ++nj) {
    const int col = n0 + wc * 64 + nj * 16 + lc;
    const float bs = bias ? bias[col] : 0.f;
    #pragma unroll
    for (int mi = 0; mi < 4; ++mi) {
      const int row = m0 + wr * 64 + mi * 16 + lr;
      #pragma unroll
      for (int i = 0; i < 4; ++i) {
        float v = acc[mi][nj][i] + bs;
        if (RELU) v = fmaxf(v, 0.f);
        if (OUT_BF16) ((u16*)C)[blockIdx.z * zCstride + (size_t)(row + i) * N + col] = f2bf(v);
        else          ((float*)C)[blockIdx.z * zCstride + (size_t)(row + i) * N + col] = v;
      }
    }
  }
}

// ---------------- 256x256 8-wave 2-phase pipelined GEMM ----------------
__device__ __forceinline__ void stage_tile256(const u16* __restrict__ src0, int K,
                                              char* ldsbase, int wave, int t) {
  const int rr = t >> 3;
  const int col = ((t & 7) ^ (rr & 7)) * 8;
  const u16* s = src0 + (size_t)rr * K + col;
  char* d = ldsbase + wave * 1024;
  #pragma unroll
  for (int j = 0; j < 4; ++j)
    gload_lds16(s + (size_t)(j * 64) * K, d + j * 8192);
}

__device__ __forceinline__ short8 lds_frag(const char* base, int row, int kkbyte) {
  return *(const short8*)(base + row * 128 + (kkbyte ^ ((row & 7) << 4)));
}

template<bool OUT_BF16, bool RELU>
__global__ __launch_bounds__(512, 2)
void k_gemm256(const u16* __restrict__ A, const u16* __restrict__ BT,
               const float* __restrict__ bias, void* __restrict__ C,
               int M, int N, int K, int nbx)
{
  extern __shared__ char lds[];
  const int t = threadIdx.x, wave = t >> 6, lane = t & 63;
  const int lg = lane >> 4, lq = lane & 15;
  const int wr = wave >> 2, wc = wave & 3;

  const int nwg = gridDim.x;
  const int sw = (blockIdx.x & 7) * (nwg >> 3) + (blockIdx.x >> 3);
  const int bx = sw % nbx, by = sw / nbx;
  const int m0 = by * 256, n0 = bx * 256;

  f32x4 acc[8][4] = {};
  short8 af[4][2], bf[4][2];

  const u16* Abase = A + (size_t)m0 * K;
  const u16* Bbase = BT + (size_t)n0 * K;

  stage_tile256(Abase, K, lds, wave, t);
  stage_tile256(Bbase, K, lds + 65536, wave, t);
  asm volatile("s_waitcnt vmcnt(0)" ::: "memory");
  __syncthreads();

  const int nkt = K >> 6;
  #pragma unroll 1
  for (int kt = 0; kt < nkt; ++kt) {
    const int cur = kt & 1;
    const char* pA = lds + cur * 32768;
    const char* pB = lds + 65536 + cur * 32768;
    char* qA = lds + (cur ^ 1) * 32768;
    char* qB = lds + 65536 + (cur ^ 1) * 32768;

    // issue next-tile staging FIRST (in-flight across all 4 quadrants)
    if (kt + 1 < nkt) {
      const int knext = (kt + 1) << 6;
      stage_tile256(Abase + knext, K, qA, wave, t);
      stage_tile256(Bbase + knext, K, qB, wave, t);
    }

    // Q0: af[m0-3] x bf[n0-1]
    #pragma unroll
    for (int m = 0; m < 4; ++m) {
      const int row = wr * 128 + m * 16 + lq;
      af[m][0] = lds_frag(pA, row, lg * 16);
      af[m][1] = lds_frag(pA, row, 64 + lg * 16);
    }
    #pragma unroll
    for (int n = 0; n < 2; ++n) {
      const int row = wc * 64 + n * 16 + lq;
      bf[n][0] = lds_frag(pB, row, lg * 16);
      bf[n][1] = lds_frag(pB, row, 64 + lg * 16);
    }
    #pragma unroll
    for (int m = 0; m < 4; ++m)
      #pragma unroll
      for (int n = 0; n < 2; ++n) {
        acc[m][n] = __builtin_amdgcn_mfma_f32_16x16x32_bf16(af[m][0], bf[n][0], acc[m][n], 0, 0, 0);
        acc[m][n] = __builtin_amdgcn_mfma_f32_16x16x32_bf16(af[m][1], bf[n][1], acc[m][n], 0, 0, 0);
      }

    // Q1: af[m0-3] x bf[n2-3]
    #pragma unroll
    for (int n = 2; n < 4; ++n) {
      const int row = wc * 64 + n * 16 + lq;
      bf[n][0] = lds_frag(pB, row, lg * 16);
      bf[n][1] = lds_frag(pB, row, 64 + lg * 16);
    }
    #pragma unroll
    for (int m = 0; m < 4; ++m)
      #pragma unroll
      for (int n = 2; n < 4; ++n) {
        acc[m][n] = __builtin_amdgcn_mfma_f32_16x16x32_bf16(af[m][0], bf[n][0], acc[m][n], 0, 0, 0);
        acc[m][n] = __builtin_amdgcn_mfma_f32_16x16x32_bf16(af[m][1], bf[n][1], acc[m][n], 0, 0, 0);
      }

    // Q2: af[m4-7] x bf[n0-1]
    #pragma unroll
    for (int m = 0; m < 4; ++m) {
      const int row = wr * 128 + (m + 4) * 16 + lq;
      af[m][0] = lds_frag(pA, row, lg * 16);
      af[m][1] = lds_frag(pA, row, 64 + lg * 16);
    }
    #pragma unroll
    for (int m = 0; m < 4; ++m)
      #pragma unroll
      for (int n = 0; n < 2; ++n) {
        acc[m + 4][n] = __builtin_amdgcn_mfma_f32_16x16x32_bf16(af[m][0], bf[n][0], acc[m + 4][n], 0, 0, 0);
        acc[m + 4][n] = __builtin_amdgcn_mfma_f32_16x16x32_bf16(af[m][1], bf[n][1], acc[m + 4][n], 0, 0, 0);
      }

    // Q3: af[m4-7] x bf[n2-3]
    #pragma unroll
    for (int m = 0; m < 4; ++m)
      #pragma unroll
      for (int n = 2; n < 4; ++n) {
        acc[m + 4][n] = __builtin_amdgcn_mfma_f32_16x16x32_bf16(af[m][0], bf[n][0], acc[m + 4][n], 0, 0, 0);
        acc[m + 4][n] = __builtin_amdgcn_mfma_f32_16x16x32_bf16(af[m][1], bf[n][1], acc[m + 4][n], 0, 0, 0);
      }

    // single sync point per K-tile: prefetch drained, everyone done reading
    asm volatile("s_waitcnt vmcnt(0)" ::: "memory");
    __syncthreads();
  }

  #pragma unroll
  for (int n = 0; n < 4; ++n) {
    const int col = n0 + wc * 64 + n * 16 + lq;
    const float bs = bias[col];
    #pragma unroll
    for (int m = 0; m < 8; ++m) {
      const int row = m0 + wr * 128 + m * 16 + lg * 4;
      #pragma unroll
      for (int i = 0; i < 4; ++i) {
        float v = acc[m][n][i] + bs;
        if (RELU) v = fmaxf(v, 0.f);
        if (OUT_BF16) ((u16*)C)[(size_t)(row + i) * N + col] = f2bf(v);
        else          ((float*)C)[(size_t)(row + i) * N + col] = v;
      }
    }
  }
}

// ---------------- flash attention v3: no K/V LDS, no barriers ----------------
// Fragments gathered directly from global (L1/L2-resident tiles).
__global__ __launch_bounds__(256)
void k_flash_attn(const u16* __restrict__ qkv, const u16* __restrict__ Vt,
                  u16* __restrict__ vw)
{
  __shared__ u16 P_lds[4][16 * 72];    // per-wave, no cross-wave access -> no barriers

  const int qb = 31 - blockIdx.x;      // LPT: longest causal chains first
  const int bh = blockIdx.y;
  const int b = bh >> 4, h = bh & 15;
  const int t = threadIdx.x, wave = t >> 6, lane = t & 63;
  const int lg = lane >> 4, lq = lane & 15;

  const int q0w = qb * 64 + wave * 16;
  short8 bq[2];
  {
    const u16* qrow = qkv + ((size_t)(b * NS + q0w + lq)) * 3072 + h * 64 + lg * 8;
    bq[0] = *(const short8*)(qrow);
    bq[1] = *(const short8*)(qrow + 32);
  }

  f32x4 o_acc[4] = {};
  float m_run = -1e30f, l_run = 0.f;

  const u16* kbase = qkv + (size_t)b * NS * 3072 + 1024 + h * 64 + lg * 8;
  const u16* vtb   = Vt + ((size_t)bh * 64) * NS + lg * 8;

  for (int kt = 0; kt <= qb; ++kt) {
    const int z0 = kt * 64;

    // K fragments direct from global: A[key=kb*16+lq][c=lg*8+e (+32)]
    short8 ak[4][2];
    #pragma unroll
    for (int kb = 0; kb < 4; ++kb) {
      const u16* kr = kbase + (size_t)(z0 + kb * 16 + lq) * 3072;
      ak[kb][0] = *(const short8*)(kr);
      ak[kb][1] = *(const short8*)(kr + 32);
    }
    f32x4 s_acc[4];
    __builtin_amdgcn_s_setprio(1);
    #pragma unroll
    for (int kb = 0; kb < 4; ++kb) {
      f32x4 z = {0.f, 0.f, 0.f, 0.f};
      z = __builtin_amdgcn_mfma_f32_16x16x32_bf16(ak[kb][0], bq[0], z, 0, 0, 0);
      s_acc[kb] = __builtin_amdgcn_mfma_f32_16x16x32_bf16(ak[kb][1], bq[1], z, 0, 0, 0);
    }
    __builtin_amdgcn_s_setprio(0);

    // V fragments: issue early, consumed after softmax
    short8 vb[4][2];
    #pragma unroll
    for (int nb = 0; nb < 4; ++nb) {
      const u16* vr = vtb + (size_t)(nb * 16 + lq) * NS + z0;
      vb[nb][0] = *(const short8*)(vr);
      vb[nb][1] = *(const short8*)(vr + 32);
    }

    float sv[16];
    #pragma unroll
    for (int kb = 0; kb < 4; ++kb)
      #pragma unroll
      for (int i = 0; i < 4; ++i)
        sv[kb * 4 + i] = s_acc[kb][i] * 0.125f;

    if (kt == qb) {   // causal mask on diagonal tile
      #pragma unroll
      for (int kb = 0; kb < 4; ++kb)
        #pragma unroll
        for (int i = 0; i < 4; ++i)
          if (z0 + kb * 16 + lg * 4 + i > q0w + lq) sv[kb * 4 + i] = -1e30f;
    }

    float tm = -1e30f;
    #pragma unroll
    for (int j = 0; j < 16; ++j) tm = fmaxf(tm, sv[j]);
    tm = fmaxf(tm, __shfl_xor(tm, 16));
    tm = fmaxf(tm, __shfl_xor(tm, 32));

    // defer-max (T13): skip rescale when per-tile max growth <= 8
    if (!__all(tm <= m_run + 8.f)) {
      const float m_new = fmaxf(m_run, tm);
      const float scl = __expf(m_run - m_new);
      float s0 = __shfl(scl, lg * 4 + 0);
      float s1 = __shfl(scl, lg * 4 + 1);
      float s2 = __shfl(scl, lg * 4 + 2);
      float s3 = __shfl(scl, lg * 4 + 3);
      #pragma unroll
      for (int nb = 0; nb < 4; ++nb) {
        o_acc[nb][0] *= s0; o_acc[nb][1] *= s1;
        o_acc[nb][2] *= s2; o_acc[nb][3] *= s3;
      }
      l_run *= scl;
      m_run = m_new;
    }

    float ts = 0.f;
    #pragma unroll
    for (int j = 0; j < 16; ++j) { float p = __expf(sv[j] - m_run); sv[j] = p; ts += p; }
    ts += __shfl_xor(ts, 16);
    ts += __shfl_xor(ts, 32);
    l_run += ts;

    // P -> per-wave LDS (layout change [S^T lanes] -> [A-frag rows]), intra-wave only
    #pragma unroll
    for (int kb = 0; kb < 4; ++kb) {
      uint32_t w0 = (uint32_t)f2bf(sv[kb * 4 + 0]) | ((uint32_t)f2bf(sv[kb * 4 + 1]) << 16);
      uint32_t w1 = (uint32_t)f2bf(sv[kb * 4 + 2]) | ((uint32_t)f2bf(sv[kb * 4 + 3]) << 16);
      uint32_t* dst = (uint32_t*)&P_lds[wave][lq * 72 + kb * 16 + lg * 4];
      dst[0] = w0; dst[1] = w1;
    }
    short8 pa0 = *(const short8*)(&P_lds[wave][lq * 72 + lg * 8]);
    short8 pa1 = *(const short8*)(&P_lds[wave][lq * 72 + 32 + lg * 8]);

    __builtin_amdgcn_s_setprio(1);
    #pragma unroll
    for (int nb = 0; nb < 4; ++nb) {
      o_acc[nb] = __builtin_amdgcn_mfma_f32_16x16x32_bf16(pa0, vb[nb][0], o_acc[nb], 0, 0, 0);
      o_acc[nb] = __builtin_amdgcn_mfma_f32_16x16x32_bf16(pa1, vb[nb][1], o_acc[nb], 0, 0, 0);
    }
    __builtin_amdgcn_s_setprio(0);
  }

  #pragma unroll
  for (int i = 0; i < 4; ++i) {
    const float rl = 1.0f / __shfl(l_run, lg * 4 + i);
    const int row = q0w + lg * 4 + i;
    #pragma unroll
    for (int nb = 0; nb < 4; ++nb) {
      const int col = h * 64 + nb * 16 + lq;
      vw[((size_t)b * NS + row) * ND + col] = f2bf(o_acc[nb][i] * rl);
    }
  }
}

// ---------------- fused add + LayerNorm ----------------
template<bool WRITE_BF16>
__global__ __launch_bounds__(256)
void k_add_ln(const float* __restrict__ U, const float* __restrict__ V,
              const float* __restrict__ g, const float* __restrict__ beta,
              float* __restrict__ outf, u16* __restrict__ outb)
{
  const int row = blockIdx.x;
  const int t = threadIdx.x;
  const size_t base = (size_t)row * ND;
  float4 u = ((const float4*)(U + base))[t];
  float4 v = ((const float4*)(V + base))[t];
  float x0 = u.x + v.x, x1 = u.y + v.y, x2 = u.z + v.z, x3 = u.w + v.w;
  float s1 = x0 + x1 + x2 + x3;
  float s2 = x0*x0 + x1*x1 + x2*x2 + x3*x3;
  #pragma unroll
  for (int m = 32; m; m >>= 1) { s1 += __shfl_xor(s1, m); s2 += __shfl_xor(s2, m); }
  __shared__ float rs1[4], rs2[4];
  const int wave = t >> 6;
  if ((t & 63) == 0) { rs1[wave] = s1; rs2[wave] = s2; }
  __syncthreads();
  s1 = rs1[0] + rs1[1] + rs1[2] + rs1[3];
  s2 = rs2[0] + rs2[1] + rs2[2] + rs2[3];
  const float mean = s1 * (1.f / ND);
  const float var  = s2 * (1.f / ND) - mean * mean;
  const float rstd = rsqrtf(var + 1e-5f);
  float4 gg = ((const float4*)g)[t];
  float4 bb = ((const float4*)beta)[t];
  float y0 = gg.x * (x0 - mean) * rstd + bb.x;
  float y1 = gg.y * (x1 - mean) * rstd + bb.y;
  float y2 = gg.z * (x2 - mean) * rstd + bb.z;
  float y3 = gg.w * (x3 - mean) * rstd + bb.w;
  ((float4*)(outf + base))[t] = make_float4(y0, y1, y2, y3);
  if (WRITE_BF16) {
    uint2 ob;
    ob.x = (uint32_t)f2bf(y0) | ((uint32_t)f2bf(y1) << 16);
    ob.y = (uint32_t)f2bf(y2) | ((uint32_t)f2bf(y3) << 16);
    ((uint2*)(outb + base))[t] = ob;
  }
}

// ---------------- LN2: h = LN(U + P0 + P1 + bias) ----------------
__global__ __launch_bounds__(256)
void k_add_ln2(const float* __restrict__ U, const float* __restrict__ P0,
               const float* __restrict__ P1, const float* __restrict__ bias,
               const float* __restrict__ g, const float* __restrict__ beta,
               float* __restrict__ outf)
{
  const int row = blockIdx.x;
  const int t = threadIdx.x;
  const size_t base = (size_t)row * ND;
  float4 u  = ((const float4*)(U + base))[t];
  float4 p0 = ((const float4*)(P0 + base))[t];
  float4 p1 = ((const float4*)(P1 + base))[t];
  float4 bv = ((const float4*)bias)[t];
  float x0 = u.x + p0.x + p1.x + bv.x;
  float x1 = u.y + p0.y + p1.y + bv.y;
  float x2 = u.z + p0.z + p1.z + bv.z;
  float x3 = u.w + p0.w + p1.w + bv.w;
  float s1 = x0 + x1 + x2 + x3;
  float s2 = x0*x0 + x1*x1 + x2*x2 + x3*x3;
  #pragma unroll
  for (int m = 32; m; m >>= 1) { s1 += __shfl_xor(s1, m); s2 += __shfl_xor(s2, m); }
  __shared__ float rs1[4], rs2[4];
  const int wave = t >> 6;
  if ((t & 63) == 0) { rs1[wave] = s1; rs2[wave] = s2; }
  __syncthreads();
  s1 = rs1[0] + rs1[1] + rs1[2] + rs1[3];
  s2 = rs2[0] + rs2[1] + rs2[2] + rs2[3];
  const float mean = s1 * (1.f / ND);
  const float var  = s2 * (1.f / ND) - mean * mean;
  const float rstd = rsqrtf(var + 1e-5f);
  float4 gg = ((const float4*)g)[t];
  float4 bb = ((const float4*)beta)[t];
  float y0 = gg.x * (x0 - mean) * rstd + bb.x;
  float y1 = gg.y * (x1 - mean) * rstd + bb.y;
  float y2 = gg.z * (x2 - mean) * rstd + bb.z;
  float y3 = gg.w * (x3 - mean) * rstd + bb.w;
  ((float4*)(outf + base))[t] = make_float4(y0, y1, y2, y3);
}

extern "C" void kernel_launch(void* const* d_in, const int* in_sizes, int n_in,
                              void* d_out, int out_size, void* d_ws, size_t ws_size,
                              hipStream_t stream) {
  const float* x    = (const float*)d_in[0];
  const float* Wqkv = (const float*)d_in[2];
  const float* bqkv = (const float*)d_in[3];
  const float* Wvw  = (const float*)d_in[4];
  const float* bvw  = (const float*)d_in[5];
  const float* g1   = (const float*)d_in[6];
  const float* b1   = (const float*)d_in[7];
  const float* WA   = (const float*)d_in[8];
  const float* bA   = (const float*)d_in[9];
  const float* WB   = (const float*)d_in[10];
  const float* bB   = (const float*)d_in[11];
  const float* g2   = (const float*)d_in[12];
  const float* b2   = (const float*)d_in[13];
  float* out = (float*)d_out;

  if (ws_size < 100663296) return;
  char* ws = (char*)d_ws;
  u16*  WqkvT = (u16*)(ws + 0);          // [3072][1024] bf16 (dead after QKV)
  u16*  WvwT  = (u16*)(ws + 6291456);    // [1024][1024]      (dead after out-proj)
  u16*  WAT   = (u16*)(ws + 8388608);    // [4096][1024]      (dead after MLP-A)
  u16*  WBT   = (u16*)(ws + 16777216);   // [1024][4096]
  u16*  xb    = (u16*)(ws + 25165824);   // [4096][1024] bf16
  u16*  qkvb  = (u16*)(ws + 33554432);   // [4096][3072] bf16
  u16*  vwb   = (u16*)(ws + 58720256);   // [4096][1024] bf16
  float* a    = (float*)(ws + 67108864); // [4096][1024] f32
  float* nf   = (float*)(ws + 83886080); // [4096][1024] f32
  u16*  nb    = (u16*)(ws + 25165824);   // alias xb (dead after QKV)
  u16*  z     = (u16*)(ws + 33554432);   // [4096][4096] bf16, alias qkvb+vwb
  u16*  Vtb   = (u16*)(ws + 67108864);   // [32][64][2048] bf16, alias a (dead until out-proj)
  float* pp   = (float*)ws;              // MLP-B partials: chunk z at pp + z*16777216
                                         //   z=0 -> ws[0,16MB)  (weights there are dead)
                                         //   z=1 -> ws[64,80MB) (a is dead after LN1)

  hipError_t e2 = hipFuncSetAttribute((const void*)&k_gemm256<true, true>,
                                      hipFuncAttributeMaxDynamicSharedMemorySize, 131072);
  const bool use256 = (e2 == hipSuccess);

  // 1. casts / transposes
  k_f32_to_bf16<<<dim3(NBS * ND / 4 / 256), 256, 0, stream>>>(x, xb, NBS * ND / 4);
  k_transpose_bf16<<<dim3(3 * ND / 32, ND / 32), 256, 0, stream>>>(Wqkv, WqkvT, ND, 3 * ND);
  k_transpose_bf16<<<dim3(ND / 32, ND / 32), 256, 0, stream>>>(Wvw, WvwT, ND, ND);
  k_transpose_bf16<<<dim3(4 * ND / 32, ND / 32), 256, 0, stream>>>(WA, WAT, ND, 4 * ND);
  k_transpose_bf16<<<dim3(ND / 32, 4 * ND / 32), 256, 0, stream>>>(WB, WBT, 4 * ND, ND);

  // 2. qkv = x @ Wqkv + bqkv -> bf16 [4096][3072]  (128^2, grid 768 = 3 blocks/CU)
  k_gemm_bt<true, false><<<dim3(3 * ND / 128, NBS / 128, 1), 256, 0, stream>>>(
      xb, WqkvT, bqkv, qkvb, NBS, 3 * ND, ND, ND, 0);

  // 3. V transpose, then flash attention
  k_vt<<<dim3(NS / 64, NB * NH), 256, 0, stream>>>(qkvb, Vtb);
  k_flash_attn<<<dim3(NS / 64, NB * NH), 256, 0, stream>>>(qkvb, Vtb, vwb);

  // 4. a = vw @ Wvw + bvw -> f32
  k_gemm_bt<false, false><<<dim3(ND / 128, NBS / 128, 1), 256, 0, stream>>>(
      vwb, WvwT, bvw, a, NBS, ND, ND, ND, 0);

  // 5. n = LN(x + a) -> nf (f32) + nb (bf16)
  k_add_ln<true><<<dim3(NBS), 256, 0, stream>>>(x, a, g1, b1, nf, nb);

  // 6. z = relu(n @ WA + bA) -> bf16 [4096][4096]  (256^2 2-phase, grid 256)
  if (use256)
    k_gemm256<true, true><<<dim3((4 * ND / 256) * (NBS / 256)), 512, 131072, stream>>>(
        nb, WAT, bA, z, NBS, 4 * ND, ND, 4 * ND / 256);
  else
    k_gemm_bt<true, true><<<dim3(4 * ND / 128, NBS / 128, 1), 256, 0, stream>>>(
        nb, WAT, bA, z, NBS, 4 * ND, ND, ND, 0);

  // 7. m = z @ WB (split-K=2 partials, no bias) -> pp[0], pp[1]
  k_gemm_bt<false, false><<<dim3(ND / 128, NBS / 128, 2), 256, 0, stream>>>(
      z, WBT, nullptr, pp, NBS, ND, 4 * ND, 2 * ND, (size_t)16777216);

  // 8. h = LN(nf + p0 + p1 + bB) -> d_out
  k_add_ln2<<<dim3(NBS), 256, 0, stream>>>(nf, pp, pp + 16777216, bB, g2, b2, out);
}

// Round 5
// 257.973 us; speedup vs baseline: 1.6046x; 1.6046x over previous
//
#include <hip/hip_runtime.h>
#include <stdint.h>

typedef unsigned short u16;
typedef __attribute__((ext_vector_type(8))) short short8;
typedef __attribute__((ext_vector_type(4))) float f32x4;

#define NB 2
#define NS 2048
#define ND 1024
#define NH 16
#define NDH 64
#define NBS (NB*NS)   // 4096 rows

__device__ __forceinline__ float bf2f(u16 u) {
  union { uint32_t i; float f; } c; c.i = ((uint32_t)u) << 16; return c.f;
}
__device__ __forceinline__ u16 f2bf(float f) {
  union { float f; uint32_t i; } c; c.f = f;
  uint32_t r = (c.i + 0x7fffu + ((c.i >> 16) & 1u)) >> 16;
  return (u16)r;
}

// ---------------- f32 -> bf16 elementwise ----------------
__global__ __launch_bounds__(256)
void k_f32_to_bf16(const float* __restrict__ X, u16* __restrict__ Y, int n4) {
  int i = blockIdx.x * 256 + threadIdx.x;
  if (i >= n4) return;
  float4 v = ((const float4*)X)[i];
  uint2 o;
  o.x = (uint32_t)f2bf(v.x) | ((uint32_t)f2bf(v.y) << 16);
  o.y = (uint32_t)f2bf(v.z) | ((uint32_t)f2bf(v.w) << 16);
  ((uint2*)Y)[i] = o;
}

// ---------------- transpose f32[K][N] -> bf16[N][K] ----------------
__global__ __launch_bounds__(256)
void k_transpose_bf16(const float* __restrict__ W, u16* __restrict__ WT, int K, int N) {
  __shared__ float tile[32][33];
  const int tx = threadIdx.x & 31, ty = threadIdx.x >> 5;
  const int n0 = blockIdx.x << 5, k0 = blockIdx.y << 5;
  #pragma unroll
  for (int j = 0; j < 4; ++j)
    tile[ty + 8*j][tx] = W[(size_t)(k0 + ty + 8*j) * N + (n0 + tx)];
  __syncthreads();
  #pragma unroll
  for (int j = 0; j < 4; ++j)
    WT[(size_t)(n0 + ty + 8*j) * K + (k0 + tx)] = f2bf(tile[tx][ty + 8*j]);
}

// ---------------- transpose V out of qkv: [z][dh] -> Vt[bh][dh][z] (bf16) ----------------
__global__ __launch_bounds__(256)
void k_vt(const u16* __restrict__ qkv, u16* __restrict__ Vt) {
  __shared__ u16 tile[64][72];
  const int zb = blockIdx.x;
  const int bh = blockIdx.y;
  const int b = bh >> 4, h = bh & 15;
  const int t = threadIdx.x;
  const int r = t >> 2, seg = (t & 3) * 16;
  const u16* src = qkv + ((size_t)(b * NS + zb * 64 + r)) * 3072 + 2048 + h * 64 + seg;
  *(short8*)(&tile[r][seg])     = *(const short8*)(src);
  *(short8*)(&tile[r][seg + 8]) = *(const short8*)(src + 8);
  __syncthreads();
  const int dh = t >> 2, zs = (t & 3) * 16;
  short8 o0, o1;
  #pragma unroll
  for (int i = 0; i < 8; ++i) o0[i] = (short)tile[zs + i][dh];
  #pragma unroll
  for (int i = 0; i < 8; ++i) o1[i] = (short)tile[zs + 8 + i][dh];
  u16* dst = Vt + (size_t)(bh * 64 + dh) * NS + zb * 64 + zs;
  *(short8*)(dst)     = o0;
  *(short8*)(dst + 8) = o1;
}

// ---------------- async global->LDS, 16B ----------------
__device__ __forceinline__ void gload_lds16(const void* g, void* l) {
  __builtin_amdgcn_global_load_lds(
      (const __attribute__((address_space(1))) void*)(void*)(uintptr_t)g,
      (__attribute__((address_space(3))) void*)l, 16, 0, 0);
}

// ---------------- 128x128 bf16 MFMA GEMM (m97 structure), split-K capable ----------------
template<bool OUT_BF16, bool RELU>
__global__ __launch_bounds__(256)
void k_gemm_bt(const u16* __restrict__ A, const u16* __restrict__ BT,
               const float* __restrict__ bias, void* __restrict__ C,
               int M, int N, int Kstride, int Klen, size_t zCstride)
{
  __shared__ u16 As[128 * 64];
  __shared__ u16 Bs[128 * 64];
  const int t = threadIdx.x, wave = t >> 6, lane = t & 63;
  const int m0 = blockIdx.y * 128, n0 = blockIdx.x * 128;
  const int wr = wave >> 1, wc = wave & 1;
  const int koff = blockIdx.z * Klen;
  A  += koff;
  BT += koff;

  f32x4 acc[4][4] = {};

  int srow[4], scol[4];
  #pragma unroll
  for (int p = 0; p < 4; ++p) {
    int o = p * 4096 + wave * 1024 + lane * 16;
    int r = o >> 7;
    int cb = o & 127;
    srow[p] = r;
    scol[p] = (cb ^ ((r & 7) << 4)) >> 1;
  }

  const int nkt = Klen >> 6;
  for (int kt = 0; kt < nkt; ++kt) {
    const int k0 = kt << 6;
    #pragma unroll
    for (int p = 0; p < 4; ++p) {
      const u16* srcA = A  + (size_t)(m0 + srow[p]) * Kstride + k0 + scol[p];
      const u16* srcB = BT + (size_t)(n0 + srow[p]) * Kstride + k0 + scol[p];
      gload_lds16(srcA, (char*)As + p * 4096 + wave * 1024);
      gload_lds16(srcB, (char*)Bs + p * 4096 + wave * 1024);
    }
    asm volatile("s_waitcnt vmcnt(0)" ::: "memory");
    __syncthreads();

    #pragma unroll
    for (int kk = 0; kk < 2; ++kk) {
      const int cbase = kk * 64 + ((lane >> 4) << 4);
      short8 af[4], bf[4];
      #pragma unroll
      for (int mi = 0; mi < 4; ++mi) {
        int r = wr * 64 + mi * 16 + (lane & 15);
        af[mi] = *(const short8*)((const char*)As + r * 128 + (cbase ^ ((r & 7) << 4)));
      }
      #pragma unroll
      for (int nj = 0; nj < 4; ++nj) {
        int r = wc * 64 + nj * 16 + (lane & 15);
        bf[nj] = *(const short8*)((const char*)Bs + r * 128 + (cbase ^ ((r & 7) << 4)));
      }
      #pragma unroll
      for (int mi = 0; mi < 4; ++mi)
        #pragma unroll
        for (int nj = 0; nj < 4; ++nj)
          acc[mi][nj] = __builtin_amdgcn_mfma_f32_16x16x32_bf16(af[mi], bf[nj], acc[mi][nj], 0, 0, 0);
    }
    __syncthreads();
  }

  const int lr = (lane >> 4) << 2;
  const int lc = lane & 15;
  #pragma unroll
  for (int nj = 0; nj < 4; ++nj) {
    const int col = n0 + wc * 64 + nj * 16 + lc;
    const float bs = bias ? bias[col] : 0.f;
    #pragma unroll
    for (int mi = 0; mi < 4; ++mi) {
      const int row = m0 + wr * 64 + mi * 16 + lr;
      #pragma unroll
      for (int i = 0; i < 4; ++i) {
        float v = acc[mi][nj][i] + bs;
        if (RELU) v = fmaxf(v, 0.f);
        if (OUT_BF16) ((u16*)C)[blockIdx.z * zCstride + (size_t)(row + i) * N + col] = f2bf(v);
        else          ((float*)C)[blockIdx.z * zCstride + (size_t)(row + i) * N + col] = v;
      }
    }
  }
}

// ---------------- 256x256 8-wave 2-phase pipelined GEMM ----------------
__device__ __forceinline__ void stage_tile256(const u16* __restrict__ src0, int K,
                                              char* ldsbase, int wave, int t) {
  const int rr = t >> 3;
  const int col = ((t & 7) ^ (rr & 7)) * 8;
  const u16* s = src0 + (size_t)rr * K + col;
  char* d = ldsbase + wave * 1024;
  #pragma unroll
  for (int j = 0; j < 4; ++j)
    gload_lds16(s + (size_t)(j * 64) * K, d + j * 8192);
}

__device__ __forceinline__ short8 lds_frag(const char* base, int row, int kkbyte) {
  return *(const short8*)(base + row * 128 + (kkbyte ^ ((row & 7) << 4)));
}

template<bool OUT_BF16, bool RELU>
__global__ __launch_bounds__(512, 2)
void k_gemm256(const u16* __restrict__ A, const u16* __restrict__ BT,
               const float* __restrict__ bias, void* __restrict__ C,
               int M, int N, int K, int nbx)
{
  extern __shared__ char lds[];
  const int t = threadIdx.x, wave = t >> 6, lane = t & 63;
  const int lg = lane >> 4, lq = lane & 15;
  const int wr = wave >> 2, wc = wave & 3;

  const int nwg = gridDim.x;
  const int sw = (blockIdx.x & 7) * (nwg >> 3) + (blockIdx.x >> 3);
  const int bx = sw % nbx, by = sw / nbx;
  const int m0 = by * 256, n0 = bx * 256;

  f32x4 acc[8][4] = {};
  short8 af[4][2], bf[4][2];

  const u16* Abase = A + (size_t)m0 * K;
  const u16* Bbase = BT + (size_t)n0 * K;

  stage_tile256(Abase, K, lds, wave, t);
  stage_tile256(Bbase, K, lds + 65536, wave, t);
  asm volatile("s_waitcnt vmcnt(0)" ::: "memory");
  __syncthreads();

  const int nkt = K >> 6;
  #pragma unroll 1
  for (int kt = 0; kt < nkt; ++kt) {
    const int cur = kt & 1;
    const char* pA = lds + cur * 32768;
    const char* pB = lds + 65536 + cur * 32768;
    char* qA = lds + (cur ^ 1) * 32768;
    char* qB = lds + 65536 + (cur ^ 1) * 32768;

    if (kt + 1 < nkt) {
      const int knext = (kt + 1) << 6;
      stage_tile256(Abase + knext, K, qA, wave, t);
      stage_tile256(Bbase + knext, K, qB, wave, t);
    }

    #pragma unroll
    for (int m = 0; m < 4; ++m) {
      const int row = wr * 128 + m * 16 + lq;
      af[m][0] = lds_frag(pA, row, lg * 16);
      af[m][1] = lds_frag(pA, row, 64 + lg * 16);
    }
    #pragma unroll
    for (int n = 0; n < 2; ++n) {
      const int row = wc * 64 + n * 16 + lq;
      bf[n][0] = lds_frag(pB, row, lg * 16);
      bf[n][1] = lds_frag(pB, row, 64 + lg * 16);
    }
    #pragma unroll
    for (int m = 0; m < 4; ++m)
      #pragma unroll
      for (int n = 0; n < 2; ++n) {
        acc[m][n] = __builtin_amdgcn_mfma_f32_16x16x32_bf16(af[m][0], bf[n][0], acc[m][n], 0, 0, 0);
        acc[m][n] = __builtin_amdgcn_mfma_f32_16x16x32_bf16(af[m][1], bf[n][1], acc[m][n], 0, 0, 0);
      }

    #pragma unroll
    for (int n = 2; n < 4; ++n) {
      const int row = wc * 64 + n * 16 + lq;
      bf[n][0] = lds_frag(pB, row, lg * 16);
      bf[n][1] = lds_frag(pB, row, 64 + lg * 16);
    }
    #pragma unroll
    for (int m = 0; m < 4; ++m)
      #pragma unroll
      for (int n = 2; n < 4; ++n) {
        acc[m][n] = __builtin_amdgcn_mfma_f32_16x16x32_bf16(af[m][0], bf[n][0], acc[m][n], 0, 0, 0);
        acc[m][n] = __builtin_amdgcn_mfma_f32_16x16x32_bf16(af[m][1], bf[n][1], acc[m][n], 0, 0, 0);
      }

    #pragma unroll
    for (int m = 0; m < 4; ++m) {
      const int row = wr * 128 + (m + 4) * 16 + lq;
      af[m][0] = lds_frag(pA, row, lg * 16);
      af[m][1] = lds_frag(pA, row, 64 + lg * 16);
    }
    #pragma unroll
    for (int m = 0; m < 4; ++m)
      #pragma unroll
      for (int n = 0; n < 2; ++n) {
        acc[m + 4][n] = __builtin_amdgcn_mfma_f32_16x16x32_bf16(af[m][0], bf[n][0], acc[m + 4][n], 0, 0, 0);
        acc[m + 4][n] = __builtin_amdgcn_mfma_f32_16x16x32_bf16(af[m][1], bf[n][1], acc[m + 4][n], 0, 0, 0);
      }

    #pragma unroll
    for (int m = 0; m < 4; ++m)
      #pragma unroll
      for (int n = 2; n < 4; ++n) {
        acc[m + 4][n] = __builtin_amdgcn_mfma_f32_16x16x32_bf16(af[m][0], bf[n][0], acc[m + 4][n], 0, 0, 0);
        acc[m + 4][n] = __builtin_amdgcn_mfma_f32_16x16x32_bf16(af[m][1], bf[n][1], acc[m + 4][n], 0, 0, 0);
      }

    asm volatile("s_waitcnt vmcnt(0)" ::: "memory");
    __syncthreads();
  }

  #pragma unroll
  for (int n = 0; n < 4; ++n) {
    const int col = n0 + wc * 64 + n * 16 + lq;
    const float bs = bias[col];
    #pragma unroll
    for (int m = 0; m < 8; ++m) {
      const int row = m0 + wr * 128 + m * 16 + lg * 4;
      #pragma unroll
      for (int i = 0; i < 4; ++i) {
        float v = acc[m][n][i] + bs;
        if (RELU) v = fmaxf(v, 0.f);
        if (OUT_BF16) ((u16*)C)[(size_t)(row + i) * N + col] = f2bf(v);
        else          ((float*)C)[(size_t)(row + i) * N + col] = v;
      }
    }
  }
}

// ---------------- flash attention v4: QBLK=128, 8 waves, staged LDS K/V ----------------
// qkv bf16 [4096][3072], Vt bf16 [32][64][2048], out vw bf16 [4096][1024]
__global__ __launch_bounds__(512)
void k_flash_attn(const u16* __restrict__ qkv, const u16* __restrict__ Vt,
                  u16* __restrict__ vw)
{
  __shared__ u16 Ks[64 * 64];          // [key][c] XOR-swizzled (8KB)
  __shared__ u16 Vts[64 * 64];         // [dh][k]  XOR-swizzled (8KB)
  __shared__ u16 P_lds[8][16 * 72];    // per-wave P [q][k], padded (18.4KB)

  const int qb = 15 - (int)blockIdx.x; // LPT: longest causal chains first
  const int bh = blockIdx.y;
  const int b = bh >> 4, h = bh & 15;
  const int t = threadIdx.x, wave = t >> 6, lane = t & 63;
  const int lg = lane >> 4, lq = lane & 15;

  const int q0w = qb * 128 + wave * 16;
  short8 bq[2];
  {
    const u16* qrow = qkv + ((size_t)(b * NS + q0w + lq)) * 3072 + h * 64 + lg * 8;
    bq[0] = *(const short8*)(qrow);
    bq[1] = *(const short8*)(qrow + 32);
  }

  f32x4 o_acc[4] = {};
  float m_run = -1e30f, l_run = 0.f;

  const u16* kbase = qkv + (size_t)b * NS * 3072 + 1024 + h * 64;
  const u16* vtb   = Vt + (size_t)bh * 64 * NS;

  // 512 threads cover the 8KB K tile and 8KB V tile in one round each
  const int so = t * 16;                       // LDS byte offset this thread fills
  const int sr = so >> 7;                      // row 0..63
  const int scb = (so & 127) ^ ((sr & 7) << 4);// pre-swizzled source byte col

  const int ntiles = 2 * qb + 2;
  for (int kt = 0; kt < ntiles; ++kt) {
    const int z0 = kt * 64;
    gload_lds16(kbase + (size_t)(z0 + sr) * 3072 + (scb >> 1), (char*)Ks + wave * 1024);
    gload_lds16(vtb + (size_t)sr * NS + z0 + (scb >> 1), (char*)Vts + wave * 1024);
    asm volatile("s_waitcnt vmcnt(0)" ::: "memory");
    __syncthreads();

    if (z0 <= q0w + 15) {   // wave-uniform: this wave has unmasked work in tile
      // S^T[k][q] = K @ Q^T
      f32x4 s_acc[4];
      __builtin_amdgcn_s_setprio(1);
      #pragma unroll
      for (int kb = 0; kb < 4; ++kb) {
        const int r = kb * 16 + lq;
        const int sw = (r & 7) << 4;
        short8 ak0 = *(const short8*)((const char*)Ks + r * 128 + ((lg * 16) ^ sw));
        short8 ak1 = *(const short8*)((const char*)Ks + r * 128 + ((64 + lg * 16) ^ sw));
        f32x4 z = {0.f, 0.f, 0.f, 0.f};
        z = __builtin_amdgcn_mfma_f32_16x16x32_bf16(ak0, bq[0], z, 0, 0, 0);
        s_acc[kb] = __builtin_amdgcn_mfma_f32_16x16x32_bf16(ak1, bq[1], z, 0, 0, 0);
      }
      __builtin_amdgcn_s_setprio(0);

      float sv[16];
      #pragma unroll
      for (int kb = 0; kb < 4; ++kb)
        #pragma unroll
        for (int i = 0; i < 4; ++i)
          sv[kb * 4 + i] = s_acc[kb][i] * 0.125f;

      if (z0 + 63 > q0w) {   // diagonal tile: causal mask
        #pragma unroll
        for (int kb = 0; kb < 4; ++kb)
          #pragma unroll
          for (int i = 0; i < 4; ++i)
            if (z0 + kb * 16 + lg * 4 + i > q0w + lq) sv[kb * 4 + i] = -1e30f;
      }

      float tm = -1e30f;
      #pragma unroll
      for (int j = 0; j < 16; ++j) tm = fmaxf(tm, sv[j]);
      tm = fmaxf(tm, __shfl_xor(tm, 16));
      tm = fmaxf(tm, __shfl_xor(tm, 32));

      // defer-max (T13)
      if (!__all(tm <= m_run + 8.f)) {
        const float m_new = fmaxf(m_run, tm);
        const float scl = __expf(m_run - m_new);
        float s0 = __shfl(scl, lg * 4 + 0);
        float s1 = __shfl(scl, lg * 4 + 1);
        float s2 = __shfl(scl, lg * 4 + 2);
        float s3 = __shfl(scl, lg * 4 + 3);
        #pragma unroll
        for (int nb = 0; nb < 4; ++nb) {
          o_acc[nb][0] *= s0; o_acc[nb][1] *= s1;
          o_acc[nb][2] *= s2; o_acc[nb][3] *= s3;
        }
        l_run *= scl;
        m_run = m_new;
      }

      float ts = 0.f;
      #pragma unroll
      for (int j = 0; j < 16; ++j) { float p = __expf(sv[j] - m_run); sv[j] = p; ts += p; }
      ts += __shfl_xor(ts, 16);
      ts += __shfl_xor(ts, 32);
      l_run += ts;

      // P -> per-wave LDS (S^T lane layout -> A-fragment layout)
      #pragma unroll
      for (int kb = 0; kb < 4; ++kb) {
        uint32_t w0 = (uint32_t)f2bf(sv[kb * 4 + 0]) | ((uint32_t)f2bf(sv[kb * 4 + 1]) << 16);
        uint32_t w1 = (uint32_t)f2bf(sv[kb * 4 + 2]) | ((uint32_t)f2bf(sv[kb * 4 + 3]) << 16);
        uint32_t* dst = (uint32_t*)&P_lds[wave][lq * 72 + kb * 16 + lg * 4];
        dst[0] = w0; dst[1] = w1;
      }
      short8 pa0 = *(const short8*)(&P_lds[wave][lq * 72 + lg * 8]);
      short8 pa1 = *(const short8*)(&P_lds[wave][lq * 72 + 32 + lg * 8]);

      __builtin_amdgcn_s_setprio(1);
      #pragma unroll
      for (int nb = 0; nb < 4; ++nb) {
        const int rv = nb * 16 + lq;
        const int swv = (rv & 7) << 4;
        short8 vb0 = *(const short8*)((const char*)Vts + rv * 128 + ((lg * 16) ^ swv));
        short8 vb1 = *(const short8*)((const char*)Vts + rv * 128 + ((64 + lg * 16) ^ swv));
        o_acc[nb] = __builtin_amdgcn_mfma_f32_16x16x32_bf16(pa0, vb0, o_acc[nb], 0, 0, 0);
        o_acc[nb] = __builtin_amdgcn_mfma_f32_16x16x32_bf16(pa1, vb1, o_acc[nb], 0, 0, 0);
      }
      __builtin_amdgcn_s_setprio(0);
    }
    __syncthreads();
  }

  #pragma unroll
  for (int i = 0; i < 4; ++i) {
    const float rl = 1.0f / __shfl(l_run, lg * 4 + i);
    const int row = q0w + lg * 4 + i;
    #pragma unroll
    for (int nb = 0; nb < 4; ++nb) {
      const int col = h * 64 + nb * 16 + lq;
      vw[((size_t)b * NS + row) * ND + col] = f2bf(o_acc[nb][i] * rl);
    }
  }
}

// ---------------- fused add + LayerNorm ----------------
template<bool WRITE_BF16>
__global__ __launch_bounds__(256)
void k_add_ln(const float* __restrict__ U, const float* __restrict__ V,
              const float* __restrict__ g, const float* __restrict__ beta,
              float* __restrict__ outf, u16* __restrict__ outb)
{
  const int row = blockIdx.x;
  const int t = threadIdx.x;
  const size_t base = (size_t)row * ND;
  float4 u = ((const float4*)(U + base))[t];
  float4 v = ((const float4*)(V + base))[t];
  float x0 = u.x + v.x, x1 = u.y + v.y, x2 = u.z + v.z, x3 = u.w + v.w;
  float s1 = x0 + x1 + x2 + x3;
  float s2 = x0*x0 + x1*x1 + x2*x2 + x3*x3;
  #pragma unroll
  for (int m = 32; m; m >>= 1) { s1 += __shfl_xor(s1, m); s2 += __shfl_xor(s2, m); }
  __shared__ float rs1[4], rs2[4];
  const int wave = t >> 6;
  if ((t & 63) == 0) { rs1[wave] = s1; rs2[wave] = s2; }
  __syncthreads();
  s1 = rs1[0] + rs1[1] + rs1[2] + rs1[3];
  s2 = rs2[0] + rs2[1] + rs2[2] + rs2[3];
  const float mean = s1 * (1.f / ND);
  const float var  = s2 * (1.f / ND) - mean * mean;
  const float rstd = rsqrtf(var + 1e-5f);
  float4 gg = ((const float4*)g)[t];
  float4 bb = ((const float4*)beta)[t];
  float y0 = gg.x * (x0 - mean) * rstd + bb.x;
  float y1 = gg.y * (x1 - mean) * rstd + bb.y;
  float y2 = gg.z * (x2 - mean) * rstd + bb.z;
  float y3 = gg.w * (x3 - mean) * rstd + bb.w;
  ((float4*)(outf + base))[t] = make_float4(y0, y1, y2, y3);
  if (WRITE_BF16) {
    uint2 ob;
    ob.x = (uint32_t)f2bf(y0) | ((uint32_t)f2bf(y1) << 16);
    ob.y = (uint32_t)f2bf(y2) | ((uint32_t)f2bf(y3) << 16);
    ((uint2*)(outb + base))[t] = ob;
  }
}

// ---------------- LN2: h = LN(U + P0 + P1 + bias) ----------------
__global__ __launch_bounds__(256)
void k_add_ln2(const float* __restrict__ U, const float* __restrict__ P0,
               const float* __restrict__ P1, const float* __restrict__ bias,
               const float* __restrict__ g, const float* __restrict__ beta,
               float* __restrict__ outf)
{
  const int row = blockIdx.x;
  const int t = threadIdx.x;
  const size_t base = (size_t)row * ND;
  float4 u  = ((const float4*)(U + base))[t];
  float4 p0 = ((const float4*)(P0 + base))[t];
  float4 p1 = ((const float4*)(P1 + base))[t];
  float4 bv = ((const float4*)bias)[t];
  float x0 = u.x + p0.x + p1.x + bv.x;
  float x1 = u.y + p0.y + p1.y + bv.y;
  float x2 = u.z + p0.z + p1.z + bv.z;
  float x3 = u.w + p0.w + p1.w + bv.w;
  float s1 = x0 + x1 + x2 + x3;
  float s2 = x0*x0 + x1*x1 + x2*x2 + x3*x3;
  #pragma unroll
  for (int m = 32; m; m >>= 1) { s1 += __shfl_xor(s1, m); s2 += __shfl_xor(s2, m); }
  __shared__ float rs1[4], rs2[4];
  const int wave = t >> 6;
  if ((t & 63) == 0) { rs1[wave] = s1; rs2[wave] = s2; }
  __syncthreads();
  s1 = rs1[0] + rs1[1] + rs1[2] + rs1[3];
  s2 = rs2[0] + rs2[1] + rs2[2] + rs2[3];
  const float mean = s1 * (1.f / ND);
  const float var  = s2 * (1.f / ND) - mean * mean;
  const float rstd = rsqrtf(var + 1e-5f);
  float4 gg = ((const float4*)g)[t];
  float4 bb = ((const float4*)beta)[t];
  float y0 = gg.x * (x0 - mean) * rstd + bb.x;
  float y1 = gg.y * (x1 - mean) * rstd + bb.y;
  float y2 = gg.z * (x2 - mean) * rstd + bb.z;
  float y3 = gg.w * (x3 - mean) * rstd + bb.w;
  ((float4*)(outf + base))[t] = make_float4(y0, y1, y2, y3);
}

extern "C" void kernel_launch(void* const* d_in, const int* in_sizes, int n_in,
                              void* d_out, int out_size, void* d_ws, size_t ws_size,
                              hipStream_t stream) {
  const float* x    = (const float*)d_in[0];
  const float* Wqkv = (const float*)d_in[2];
  const float* bqkv = (const float*)d_in[3];
  const float* Wvw  = (const float*)d_in[4];
  const float* bvw  = (const float*)d_in[5];
  const float* g1   = (const float*)d_in[6];
  const float* b1   = (const float*)d_in[7];
  const float* WA   = (const float*)d_in[8];
  const float* bA   = (const float*)d_in[9];
  const float* WB   = (const float*)d_in[10];
  const float* bB   = (const float*)d_in[11];
  const float* g2   = (const float*)d_in[12];
  const float* b2   = (const float*)d_in[13];
  float* out = (float*)d_out;

  if (ws_size < 100663296) return;
  char* ws = (char*)d_ws;
  u16*  WqkvT = (u16*)(ws + 0);          // [3072][1024] bf16 (dead after QKV)
  u16*  WvwT  = (u16*)(ws + 6291456);    // [1024][1024]      (dead after out-proj)
  u16*  WAT   = (u16*)(ws + 8388608);    // [4096][1024]      (dead after MLP-A)
  u16*  WBT   = (u16*)(ws + 16777216);   // [1024][4096]
  u16*  xb    = (u16*)(ws + 25165824);   // [4096][1024] bf16
  u16*  qkvb  = (u16*)(ws + 33554432);   // [4096][3072] bf16
  u16*  vwb   = (u16*)(ws + 58720256);   // [4096][1024] bf16
  float* a    = (float*)(ws + 67108864); // [4096][1024] f32
  float* nf   = (float*)(ws + 83886080); // [4096][1024] f32
  u16*  nb    = (u16*)(ws + 25165824);   // alias xb (dead after QKV)
  u16*  z     = (u16*)(ws + 33554432);   // [4096][4096] bf16, alias qkvb+vwb
  u16*  Vtb   = (u16*)(ws + 67108864);   // [32][64][2048] bf16, alias a
  float* pp   = (float*)ws;              // MLP-B partials (z=0 -> ws[0,16MB), z=1 -> ws[64,80MB))

  hipError_t e2 = hipFuncSetAttribute((const void*)&k_gemm256<true, true>,
                                      hipFuncAttributeMaxDynamicSharedMemorySize, 131072);
  const bool use256 = (e2 == hipSuccess);

  // 1. casts / transposes
  k_f32_to_bf16<<<dim3(NBS * ND / 4 / 256), 256, 0, stream>>>(x, xb, NBS * ND / 4);
  k_transpose_bf16<<<dim3(3 * ND / 32, ND / 32), 256, 0, stream>>>(Wqkv, WqkvT, ND, 3 * ND);
  k_transpose_bf16<<<dim3(ND / 32, ND / 32), 256, 0, stream>>>(Wvw, WvwT, ND, ND);
  k_transpose_bf16<<<dim3(4 * ND / 32, ND / 32), 256, 0, stream>>>(WA, WAT, ND, 4 * ND);
  k_transpose_bf16<<<dim3(ND / 32, 4 * ND / 32), 256, 0, stream>>>(WB, WBT, 4 * ND, ND);

  // 2. qkv = x @ Wqkv + bqkv -> bf16 [4096][3072]
  k_gemm_bt<true, false><<<dim3(3 * ND / 128, NBS / 128, 1), 256, 0, stream>>>(
      xb, WqkvT, bqkv, qkvb, NBS, 3 * ND, ND, ND, 0);

  // 3. V transpose, then flash attention (QBLK=128, 8 waves)
  k_vt<<<dim3(NS / 64, NB * NH), 256, 0, stream>>>(qkvb, Vtb);
  k_flash_attn<<<dim3(NS / 128, NB * NH), 512, 0, stream>>>(qkvb, Vtb, vwb);

  // 4. a = vw @ Wvw + bvw -> f32
  k_gemm_bt<false, false><<<dim3(ND / 128, NBS / 128, 1), 256, 0, stream>>>(
      vwb, WvwT, bvw, a, NBS, ND, ND, ND, 0);

  // 5. n = LN(x + a) -> nf (f32) + nb (bf16)
  k_add_ln<true><<<dim3(NBS), 256, 0, stream>>>(x, a, g1, b1, nf, nb);

  // 6. z = relu(n @ WA + bA) -> bf16 [4096][4096]
  if (use256)
    k_gemm256<true, true><<<dim3((4 * ND / 256) * (NBS / 256)), 512, 131072, stream>>>(
        nb, WAT, bA, z, NBS, 4 * ND, ND, 4 * ND / 256);
  else
    k_gemm_bt<true, true><<<dim3(4 * ND / 128, NBS / 128, 1), 256, 0, stream>>>(
        nb, WAT, bA, z, NBS, 4 * ND, ND, ND, 0);

  // 7. m = z @ WB (split-K=2 partials, no bias) -> pp[0], pp[1]
  k_gemm_bt<false, false><<<dim3(ND / 128, NBS / 128, 2), 256, 0, stream>>>(
      z, WBT, nullptr, pp, NBS, ND, 4 * ND, 2 * ND, (size_t)16777216);

  // 8. h = LN(nf + p0 + p1 + bB) -> d_out
  k_add_ln2<<<dim3(NBS), 256, 0, stream>>>(nf, pp, pp + 16777216, bB, g2, b2, out);
}

// Round 6
// 240.383 us; speedup vs baseline: 1.7220x; 1.0732x over previous
//
#include <hip/hip_runtime.h>
#include <stdint.h>

typedef unsigned short u16;
typedef __attribute__((ext_vector_type(8))) short short8;
typedef __attribute__((ext_vector_type(4))) float f32x4;

#define NB 2
#define NS 2048
#define ND 1024
#define NH 16
#define NDH 64
#define NBS (NB*NS)   // 4096 rows

__device__ __forceinline__ float bf2f(u16 u) {
  union { uint32_t i; float f; } c; c.i = ((uint32_t)u) << 16; return c.f;
}
__device__ __forceinline__ u16 f2bf(float f) {
  union { float f; uint32_t i; } c; c.f = f;
  uint32_t r = (c.i + 0x7fffu + ((c.i >> 16) & 1u)) >> 16;
  return (u16)r;
}

// ---------------- f32 -> bf16 elementwise ----------------
__global__ __launch_bounds__(256)
void k_f32_to_bf16(const float* __restrict__ X, u16* __restrict__ Y, int n4) {
  int i = blockIdx.x * 256 + threadIdx.x;
  if (i >= n4) return;
  float4 v = ((const float4*)X)[i];
  uint2 o;
  o.x = (uint32_t)f2bf(v.x) | ((uint32_t)f2bf(v.y) << 16);
  o.y = (uint32_t)f2bf(v.z) | ((uint32_t)f2bf(v.w) << 16);
  ((uint2*)Y)[i] = o;
}

// ---------------- all weight transposes in one launch: f32[K][N] -> bf16[N][K] ----------------
__global__ __launch_bounds__(256)
void k_transpose_all(const float* __restrict__ Wqkv, const float* __restrict__ Wvw,
                     const float* __restrict__ WA, const float* __restrict__ WB,
                     u16* __restrict__ WqkvT, u16* __restrict__ WvwT,
                     u16* __restrict__ WAT, u16* __restrict__ WBT) {
  __shared__ float tile[32][33];
  int id = blockIdx.x;
  const float* W; u16* WT; int K, N, tid;
  if (id < 3072)      { W = Wqkv; WT = WqkvT; K = 1024; N = 3072; tid = id; }
  else if (id < 4096) { W = Wvw;  WT = WvwT;  K = 1024; N = 1024; tid = id - 3072; }
  else if (id < 8192) { W = WA;   WT = WAT;   K = 1024; N = 4096; tid = id - 4096; }
  else                { W = WB;   WT = WBT;   K = 4096; N = 1024; tid = id - 8192; }
  const int ntx = N >> 5;
  const int n0 = (tid % ntx) << 5, k0 = (tid / ntx) << 5;
  const int tx = threadIdx.x & 31, ty = threadIdx.x >> 5;
  #pragma unroll
  for (int j = 0; j < 4; ++j)
    tile[ty + 8*j][tx] = W[(size_t)(k0 + ty + 8*j) * N + (n0 + tx)];
  __syncthreads();
  #pragma unroll
  for (int j = 0; j < 4; ++j)
    WT[(size_t)(n0 + ty + 8*j) * K + (k0 + tx)] = f2bf(tile[tx][ty + 8*j]);
}

// ---------------- transpose V out of qkv: [z][dh] -> Vt[bh][dh][z] (bf16) ----------------
__global__ __launch_bounds__(256)
void k_vt(const u16* __restrict__ qkv, u16* __restrict__ Vt) {
  __shared__ u16 tile[64][72];
  const int zb = blockIdx.x;
  const int bh = blockIdx.y;
  const int b = bh >> 4, h = bh & 15;
  const int t = threadIdx.x;
  const int r = t >> 2, seg = (t & 3) * 16;
  const u16* src = qkv + ((size_t)(b * NS + zb * 64 + r)) * 3072 + 2048 + h * 64 + seg;
  *(short8*)(&tile[r][seg])     = *(const short8*)(src);
  *(short8*)(&tile[r][seg + 8]) = *(const short8*)(src + 8);
  __syncthreads();
  const int dh = t >> 2, zs = (t & 3) * 16;
  short8 o0, o1;
  #pragma unroll
  for (int i = 0; i < 8; ++i) o0[i] = (short)tile[zs + i][dh];
  #pragma unroll
  for (int i = 0; i < 8; ++i) o1[i] = (short)tile[zs + 8 + i][dh];
  u16* dst = Vt + (size_t)(bh * 64 + dh) * NS + zb * 64 + zs;
  *(short8*)(dst)     = o0;
  *(short8*)(dst + 8) = o1;
}

// ---------------- async global->LDS, 16B ----------------
__device__ __forceinline__ void gload_lds16(const void* g, void* l) {
  __builtin_amdgcn_global_load_lds(
      (const __attribute__((address_space(1))) void*)(void*)(uintptr_t)g,
      (__attribute__((address_space(3))) void*)l, 16, 0, 0);
}

// ---------------- 128x128 bf16 MFMA GEMM (m97 structure), split-K capable ----------------
template<bool OUT_BF16, bool RELU>
__global__ __launch_bounds__(256)
void k_gemm_bt(const u16* __restrict__ A, const u16* __restrict__ BT,
               const float* __restrict__ bias, void* __restrict__ C,
               int M, int N, int Kstride, int Klen, size_t zCstride)
{
  __shared__ u16 As[128 * 64];
  __shared__ u16 Bs[128 * 64];
  const int t = threadIdx.x, wave = t >> 6, lane = t & 63;
  const int m0 = blockIdx.y * 128, n0 = blockIdx.x * 128;
  const int wr = wave >> 1, wc = wave & 1;
  const int koff = blockIdx.z * Klen;
  A  += koff;
  BT += koff;

  f32x4 acc[4][4] = {};

  int srow[4], scol[4];
  #pragma unroll
  for (int p = 0; p < 4; ++p) {
    int o = p * 4096 + wave * 1024 + lane * 16;
    int r = o >> 7;
    int cb = o & 127;
    srow[p] = r;
    scol[p] = (cb ^ ((r & 7) << 4)) >> 1;
  }

  const int nkt = Klen >> 6;
  for (int kt = 0; kt < nkt; ++kt) {
    const int k0 = kt << 6;
    #pragma unroll
    for (int p = 0; p < 4; ++p) {
      const u16* srcA = A  + (size_t)(m0 + srow[p]) * Kstride + k0 + scol[p];
      const u16* srcB = BT + (size_t)(n0 + srow[p]) * Kstride + k0 + scol[p];
      gload_lds16(srcA, (char*)As + p * 4096 + wave * 1024);
      gload_lds16(srcB, (char*)Bs + p * 4096 + wave * 1024);
    }
    asm volatile("s_waitcnt vmcnt(0)" ::: "memory");
    __syncthreads();

    #pragma unroll
    for (int kk = 0; kk < 2; ++kk) {
      const int cbase = kk * 64 + ((lane >> 4) << 4);
      short8 af[4], bf[4];
      #pragma unroll
      for (int mi = 0; mi < 4; ++mi) {
        int r = wr * 64 + mi * 16 + (lane & 15);
        af[mi] = *(const short8*)((const char*)As + r * 128 + (cbase ^ ((r & 7) << 4)));
      }
      #pragma unroll
      for (int nj = 0; nj < 4; ++nj) {
        int r = wc * 64 + nj * 16 + (lane & 15);
        bf[nj] = *(const short8*)((const char*)Bs + r * 128 + (cbase ^ ((r & 7) << 4)));
      }
      #pragma unroll
      for (int mi = 0; mi < 4; ++mi)
        #pragma unroll
        for (int nj = 0; nj < 4; ++nj)
          acc[mi][nj] = __builtin_amdgcn_mfma_f32_16x16x32_bf16(af[mi], bf[nj], acc[mi][nj], 0, 0, 0);
    }
    __syncthreads();
  }

  const int lr = (lane >> 4) << 2;
  const int lc = lane & 15;
  #pragma unroll
  for (int nj = 0; nj < 4; ++nj) {
    const int col = n0 + wc * 64 + nj * 16 + lc;
    const float bs = bias ? bias[col] : 0.f;
    #pragma unroll
    for (int mi = 0; mi < 4; ++mi) {
      const int row = m0 + wr * 64 + mi * 16 + lr;
      #pragma unroll
      for (int i = 0; i < 4; ++i) {
        float v = acc[mi][nj][i] + bs;
        if (RELU) v = fmaxf(v, 0.f);
        if (OUT_BF16) ((u16*)C)[blockIdx.z * zCstride + (size_t)(row + i) * N + col] = f2bf(v);
        else          ((float*)C)[blockIdx.z * zCstride + (size_t)(row + i) * N + col] = v;
      }
    }
  }
}

// ---------------- 256x256 8-wave 2-phase pipelined GEMM ----------------
__device__ __forceinline__ void stage_tile256(const u16* __restrict__ src0, int K,
                                              char* ldsbase, int wave, int t) {
  const int rr = t >> 3;
  const int col = ((t & 7) ^ (rr & 7)) * 8;
  const u16* s = src0 + (size_t)rr * K + col;
  char* d = ldsbase + wave * 1024;
  #pragma unroll
  for (int j = 0; j < 4; ++j)
    gload_lds16(s + (size_t)(j * 64) * K, d + j * 8192);
}

__device__ __forceinline__ short8 lds_frag(const char* base, int row, int kkbyte) {
  return *(const short8*)(base + row * 128 + (kkbyte ^ ((row & 7) << 4)));
}

template<bool OUT_BF16, bool RELU>
__global__ __launch_bounds__(512, 2)
void k_gemm256(const u16* __restrict__ A, const u16* __restrict__ BT,
               const float* __restrict__ bias, void* __restrict__ C,
               int M, int N, int K, int nbx)
{
  extern __shared__ char lds[];
  const int t = threadIdx.x, wave = t >> 6, lane = t & 63;
  const int lg = lane >> 4, lq = lane & 15;
  const int wr = wave >> 2, wc = wave & 3;

  const int nwg = gridDim.x;
  const int sw = (blockIdx.x & 7) * (nwg >> 3) + (blockIdx.x >> 3);
  const int bx = sw % nbx, by = sw / nbx;
  const int m0 = by * 256, n0 = bx * 256;

  f32x4 acc[8][4] = {};
  short8 af[4][2], bf[4][2];

  const u16* Abase = A + (size_t)m0 * K;
  const u16* Bbase = BT + (size_t)n0 * K;

  stage_tile256(Abase, K, lds, wave, t);
  stage_tile256(Bbase, K, lds + 65536, wave, t);
  asm volatile("s_waitcnt vmcnt(0)" ::: "memory");
  __syncthreads();

  const int nkt = K >> 6;
  #pragma unroll 1
  for (int kt = 0; kt < nkt; ++kt) {
    const int cur = kt & 1;
    const char* pA = lds + cur * 32768;
    const char* pB = lds + 65536 + cur * 32768;
    char* qA = lds + (cur ^ 1) * 32768;
    char* qB = lds + 65536 + (cur ^ 1) * 32768;

    if (kt + 1 < nkt) {
      const int knext = (kt + 1) << 6;
      stage_tile256(Abase + knext, K, qA, wave, t);
      stage_tile256(Bbase + knext, K, qB, wave, t);
    }

    #pragma unroll
    for (int m = 0; m < 4; ++m) {
      const int row = wr * 128 + m * 16 + lq;
      af[m][0] = lds_frag(pA, row, lg * 16);
      af[m][1] = lds_frag(pA, row, 64 + lg * 16);
    }
    #pragma unroll
    for (int n = 0; n < 2; ++n) {
      const int row = wc * 64 + n * 16 + lq;
      bf[n][0] = lds_frag(pB, row, lg * 16);
      bf[n][1] = lds_frag(pB, row, 64 + lg * 16);
    }
    #pragma unroll
    for (int m = 0; m < 4; ++m)
      #pragma unroll
      for (int n = 0; n < 2; ++n) {
        acc[m][n] = __builtin_amdgcn_mfma_f32_16x16x32_bf16(af[m][0], bf[n][0], acc[m][n], 0, 0, 0);
        acc[m][n] = __builtin_amdgcn_mfma_f32_16x16x32_bf16(af[m][1], bf[n][1], acc[m][n], 0, 0, 0);
      }

    #pragma unroll
    for (int n = 2; n < 4; ++n) {
      const int row = wc * 64 + n * 16 + lq;
      bf[n][0] = lds_frag(pB, row, lg * 16);
      bf[n][1] = lds_frag(pB, row, 64 + lg * 16);
    }
    #pragma unroll
    for (int m = 0; m < 4; ++m)
      #pragma unroll
      for (int n = 2; n < 4; ++n) {
        acc[m][n] = __builtin_amdgcn_mfma_f32_16x16x32_bf16(af[m][0], bf[n][0], acc[m][n], 0, 0, 0);
        acc[m][n] = __builtin_amdgcn_mfma_f32_16x16x32_bf16(af[m][1], bf[n][1], acc[m][n], 0, 0, 0);
      }

    #pragma unroll
    for (int m = 0; m < 4; ++m) {
      const int row = wr * 128 + (m + 4) * 16 + lq;
      af[m][0] = lds_frag(pA, row, lg * 16);
      af[m][1] = lds_frag(pA, row, 64 + lg * 16);
    }
    #pragma unroll
    for (int m = 0; m < 4; ++m)
      #pragma unroll
      for (int n = 0; n < 2; ++n) {
        acc[m + 4][n] = __builtin_amdgcn_mfma_f32_16x16x32_bf16(af[m][0], bf[n][0], acc[m + 4][n], 0, 0, 0);
        acc[m + 4][n] = __builtin_amdgcn_mfma_f32_16x16x32_bf16(af[m][1], bf[n][1], acc[m + 4][n], 0, 0, 0);
      }

    #pragma unroll
    for (int m = 0; m < 4; ++m)
      #pragma unroll
      for (int n = 2; n < 4; ++n) {
        acc[m + 4][n] = __builtin_amdgcn_mfma_f32_16x16x32_bf16(af[m][0], bf[n][0], acc[m + 4][n], 0, 0, 0);
        acc[m + 4][n] = __builtin_amdgcn_mfma_f32_16x16x32_bf16(af[m][1], bf[n][1], acc[m + 4][n], 0, 0, 0);
      }

    asm volatile("s_waitcnt vmcnt(0)" ::: "memory");
    __syncthreads();
  }

  #pragma unroll
  for (int n = 0; n < 4; ++n) {
    const int col = n0 + wc * 64 + n * 16 + lq;
    const float bs = bias[col];
    #pragma unroll
    for (int m = 0; m < 8; ++m) {
      const int row = m0 + wr * 128 + m * 16 + lg * 4;
      #pragma unroll
      for (int i = 0; i < 4; ++i) {
        float v = acc[m][n][i] + bs;
        if (RELU) v = fmaxf(v, 0.f);
        if (OUT_BF16) ((u16*)C)[(size_t)(row + i) * N + col] = f2bf(v);
        else          ((float*)C)[(size_t)(row + i) * N + col] = v;
      }
    }
  }
}

// ---------------- flash attention v5: QBLK=128, 8 waves, paired KV tiles, log2 softmax ----------------
__global__ __launch_bounds__(512)
void k_flash_attn(const u16* __restrict__ qkv, const u16* __restrict__ Vt,
                  u16* __restrict__ vw)
{
  __shared__ u16 Ks[2][64 * 64];       // two sub-tiles of the pair (16KB)
  __shared__ u16 Vts[2][64 * 64];      // (16KB)
  __shared__ u16 P_lds[8][16 * 72];    // per-wave P [q][k], padded (18.4KB)

  const int qb = 15 - (int)blockIdx.x; // LPT: longest causal chains first
  const int bh = blockIdx.y;
  const int b = bh >> 4, h = bh & 15;
  const int t = threadIdx.x, wave = t >> 6, lane = t & 63;
  const int lg = lane >> 4, lq = lane & 15;

  const int q0w = qb * 128 + wave * 16;

  // Q fragment pre-scaled by 1/sqrt(dh)*log2(e): QK^T lands in log2 domain
  const float QSC = 0.18033688f;       // 0.125 * log2(e)
  short8 bq[2];
  {
    const u16* qrow = qkv + ((size_t)(b * NS + q0w + lq)) * 3072 + h * 64 + lg * 8;
    short8 r0 = *(const short8*)(qrow);
    short8 r1 = *(const short8*)(qrow + 32);
    union { short8 s; uint32_t u[4]; } o0, o1;
    #pragma unroll
    for (int p = 0; p < 4; ++p) {
      float a0 = bf2f((u16)r0[2*p]) * QSC, a1 = bf2f((u16)r0[2*p+1]) * QSC;
      float c0 = bf2f((u16)r1[2*p]) * QSC, c1 = bf2f((u16)r1[2*p+1]) * QSC;
      asm("v_cvt_pk_bf16_f32 %0, %1, %2" : "=v"(o0.u[p]) : "v"(a0), "v"(a1));
      asm("v_cvt_pk_bf16_f32 %0, %1, %2" : "=v"(o1.u[p]) : "v"(c0), "v"(c1));
    }
    bq[0] = o0.s; bq[1] = o1.s;
  }

  f32x4 o_acc[4] = {};
  float m_run = -1e30f, l_run = 0.f;

  const u16* kbase = qkv + (size_t)b * NS * 3072 + 1024 + h * 64;
  const u16* vtb   = Vt + (size_t)bh * 64 * NS;

  const int so = t * 16;                        // staging slice (512 thr cover 8KB tile)
  const int sr = so >> 7;
  const int scb = (so & 127) ^ ((sr & 7) << 4);
  const int npairs = qb + 1;

  for (int kp = 0; kp < npairs; ++kp) {
    const int z0 = kp * 128;
    gload_lds16(kbase + (size_t)(z0 + sr) * 3072 + (scb >> 1),      (char*)Ks[0] + wave * 1024);
    gload_lds16(kbase + (size_t)(z0 + 64 + sr) * 3072 + (scb >> 1), (char*)Ks[1] + wave * 1024);
    gload_lds16(vtb + (size_t)sr * NS + z0 + (scb >> 1),            (char*)Vts[0] + wave * 1024);
    gload_lds16(vtb + (size_t)sr * NS + z0 + 64 + (scb >> 1),       (char*)Vts[1] + wave * 1024);
    asm volatile("s_waitcnt vmcnt(0)" ::: "memory");
    __syncthreads();

    #pragma unroll
    for (int sub = 0; sub < 2; ++sub) {
      const int zz = z0 + (sub << 6);
      if (zz <= q0w + 15) {              // wave-uniform gate
        // S^T[k][q] = K @ Q^T  (log2 units)
        f32x4 s_acc[4];
        __builtin_amdgcn_s_setprio(1);
        #pragma unroll
        for (int kb = 0; kb < 4; ++kb) {
          const int r = kb * 16 + lq;
          const int sw = (r & 7) << 4;
          short8 ak0 = *(const short8*)((const char*)Ks[sub] + r * 128 + ((lg * 16) ^ sw));
          short8 ak1 = *(const short8*)((const char*)Ks[sub] + r * 128 + ((64 + lg * 16) ^ sw));
          f32x4 zr = {0.f, 0.f, 0.f, 0.f};
          zr = __builtin_amdgcn_mfma_f32_16x16x32_bf16(ak0, bq[0], zr, 0, 0, 0);
          s_acc[kb] = __builtin_amdgcn_mfma_f32_16x16x32_bf16(ak1, bq[1], zr, 0, 0, 0);
        }
        __builtin_amdgcn_s_setprio(0);

        float sv[16];
        #pragma unroll
        for (int kb = 0; kb < 4; ++kb)
          #pragma unroll
          for (int i = 0; i < 4; ++i)
            sv[kb * 4 + i] = s_acc[kb][i];

        if (zz + 63 > q0w) {             // diagonal tile: causal mask
          #pragma unroll
          for (int kb = 0; kb < 4; ++kb)
            #pragma unroll
            for (int i = 0; i < 4; ++i)
              if (zz + kb * 16 + lg * 4 + i > q0w + lq) sv[kb * 4 + i] = -1e30f;
        }

        float tm = -1e30f;
        #pragma unroll
        for (int j = 0; j < 16; ++j) tm = fmaxf(tm, sv[j]);
        tm = fmaxf(tm, __shfl_xor(tm, 16));
        tm = fmaxf(tm, __shfl_xor(tm, 32));

        // defer-max (T13): threshold 8 nats = 11.54 log2-units
        if (!__all(tm <= m_run + 11.5415603f)) {
          const float m_new = fmaxf(m_run, tm);
          const float scl = __builtin_amdgcn_exp2f(m_run - m_new);
          float s0 = __shfl(scl, lg * 4 + 0);
          float s1 = __shfl(scl, lg * 4 + 1);
          float s2 = __shfl(scl, lg * 4 + 2);
          float s3 = __shfl(scl, lg * 4 + 3);
          #pragma unroll
          for (int nb = 0; nb < 4; ++nb) {
            o_acc[nb][0] *= s0; o_acc[nb][1] *= s1;
            o_acc[nb][2] *= s2; o_acc[nb][3] *= s3;
          }
          l_run *= scl;
          m_run = m_new;
        }

        float ts = 0.f;
        #pragma unroll
        for (int j = 0; j < 16; ++j) {
          float p = __builtin_amdgcn_exp2f(sv[j] - m_run);
          sv[j] = p; ts += p;
        }
        ts += __shfl_xor(ts, 16);
        ts += __shfl_xor(ts, 32);
        l_run += ts;

        // P -> per-wave LDS via cvt_pk (S^T lane layout -> A-fragment layout)
        #pragma unroll
        for (int kb = 0; kb < 4; ++kb) {
          uint32_t w0, w1;
          asm("v_cvt_pk_bf16_f32 %0, %1, %2" : "=v"(w0) : "v"(sv[kb*4+0]), "v"(sv[kb*4+1]));
          asm("v_cvt_pk_bf16_f32 %0, %1, %2" : "=v"(w1) : "v"(sv[kb*4+2]), "v"(sv[kb*4+3]));
          uint32_t* dst = (uint32_t*)&P_lds[wave][lq * 72 + kb * 16 + lg * 4];
          dst[0] = w0; dst[1] = w1;
        }
        short8 pa0 = *(const short8*)(&P_lds[wave][lq * 72 + lg * 8]);
        short8 pa1 = *(const short8*)(&P_lds[wave][lq * 72 + 32 + lg * 8]);

        __builtin_amdgcn_s_setprio(1);
        #pragma unroll
        for (int nb = 0; nb < 4; ++nb) {
          const int rv = nb * 16 + lq;
          const int swv = (rv & 7) << 4;
          short8 vb0 = *(const short8*)((const char*)Vts[sub] + rv * 128 + ((lg * 16) ^ swv));
          short8 vb1 = *(const short8*)((const char*)Vts[sub] + rv * 128 + ((64 + lg * 16) ^ swv));
          o_acc[nb] = __builtin_amdgcn_mfma_f32_16x16x32_bf16(pa0, vb0, o_acc[nb], 0, 0, 0);
          o_acc[nb] = __builtin_amdgcn_mfma_f32_16x16x32_bf16(pa1, vb1, o_acc[nb], 0, 0, 0);
        }
        __builtin_amdgcn_s_setprio(0);
      }
    }
    __syncthreads();
  }

  #pragma unroll
  for (int i = 0; i < 4; ++i) {
    const float rl = 1.0f / __shfl(l_run, lg * 4 + i);
    const int row = q0w + lg * 4 + i;
    #pragma unroll
    for (int nb = 0; nb < 4; ++nb) {
      const int col = h * 64 + nb * 16 + lq;
      vw[((size_t)b * NS + row) * ND + col] = f2bf(o_acc[nb][i] * rl);
    }
  }
}

// ---------------- fused add + LayerNorm ----------------
template<bool WRITE_BF16>
__global__ __launch_bounds__(256)
void k_add_ln(const float* __restrict__ U, const float* __restrict__ V,
              const float* __restrict__ g, const float* __restrict__ beta,
              float* __restrict__ outf, u16* __restrict__ outb)
{
  const int row = blockIdx.x;
  const int t = threadIdx.x;
  const size_t base = (size_t)row * ND;
  float4 u = ((const float4*)(U + base))[t];
  float4 v = ((const float4*)(V + base))[t];
  float x0 = u.x + v.x, x1 = u.y + v.y, x2 = u.z + v.z, x3 = u.w + v.w;
  float s1 = x0 + x1 + x2 + x3;
  float s2 = x0*x0 + x1*x1 + x2*x2 + x3*x3;
  #pragma unroll
  for (int m = 32; m; m >>= 1) { s1 += __shfl_xor(s1, m); s2 += __shfl_xor(s2, m); }
  __shared__ float rs1[4], rs2[4];
  const int wave = t >> 6;
  if ((t & 63) == 0) { rs1[wave] = s1; rs2[wave] = s2; }
  __syncthreads();
  s1 = rs1[0] + rs1[1] + rs1[2] + rs1[3];
  s2 = rs2[0] + rs2[1] + rs2[2] + rs2[3];
  const float mean = s1 * (1.f / ND);
  const float var  = s2 * (1.f / ND) - mean * mean;
  const float rstd = rsqrtf(var + 1e-5f);
  float4 gg = ((const float4*)g)[t];
  float4 bb = ((const float4*)beta)[t];
  float y0 = gg.x * (x0 - mean) * rstd + bb.x;
  float y1 = gg.y * (x1 - mean) * rstd + bb.y;
  float y2 = gg.z * (x2 - mean) * rstd + bb.z;
  float y3 = gg.w * (x3 - mean) * rstd + bb.w;
  ((float4*)(outf + base))[t] = make_float4(y0, y1, y2, y3);
  if (WRITE_BF16) {
    uint2 ob;
    ob.x = (uint32_t)f2bf(y0) | ((uint32_t)f2bf(y1) << 16);
    ob.y = (uint32_t)f2bf(y2) | ((uint32_t)f2bf(y3) << 16);
    ((uint2*)(outb + base))[t] = ob;
  }
}

// ---------------- LN2: h = LN(U + P0 + P1 + bias) ----------------
__global__ __launch_bounds__(256)
void k_add_ln2(const float* __restrict__ U, const float* __restrict__ P0,
               const float* __restrict__ P1, const float* __restrict__ bias,
               const float* __restrict__ g, const float* __restrict__ beta,
               float* __restrict__ outf)
{
  const int row = blockIdx.x;
  const int t = threadIdx.x;
  const size_t base = (size_t)row * ND;
  float4 u  = ((const float4*)(U + base))[t];
  float4 p0 = ((const float4*)(P0 + base))[t];
  float4 p1 = ((const float4*)(P1 + base))[t];
  float4 bv = ((const float4*)bias)[t];
  float x0 = u.x + p0.x + p1.x + bv.x;
  float x1 = u.y + p0.y + p1.y + bv.y;
  float x2 = u.z + p0.z + p1.z + bv.z;
  float x3 = u.w + p0.w + p1.w + bv.w;
  float s1 = x0 + x1 + x2 + x3;
  float s2 = x0*x0 + x1*x1 + x2*x2 + x3*x3;
  #pragma unroll
  for (int m = 32; m; m >>= 1) { s1 += __shfl_xor(s1, m); s2 += __shfl_xor(s2, m); }
  __shared__ float rs1[4], rs2[4];
  const int wave = t >> 6;
  if ((t & 63) == 0) { rs1[wave] = s1; rs2[wave] = s2; }
  __syncthreads();
  s1 = rs1[0] + rs1[1] + rs1[2] + rs1[3];
  s2 = rs2[0] + rs2[1] + rs2[2] + rs2[3];
  const float mean = s1 * (1.f / ND);
  const float var  = s2 * (1.f / ND) - mean * mean;
  const float rstd = rsqrtf(var + 1e-5f);
  float4 gg = ((const float4*)g)[t];
  float4 bb = ((const float4*)beta)[t];
  float y0 = gg.x * (x0 - mean) * rstd + bb.x;
  float y1 = gg.y * (x1 - mean) * rstd + bb.y;
  float y2 = gg.z * (x2 - mean) * rstd + bb.z;
  float y3 = gg.w * (x3 - mean) * rstd + bb.w;
  ((float4*)(outf + base))[t] = make_float4(y0, y1, y2, y3);
}

extern "C" void kernel_launch(void* const* d_in, const int* in_sizes, int n_in,
                              void* d_out, int out_size, void* d_ws, size_t ws_size,
                              hipStream_t stream) {
  const float* x    = (const float*)d_in[0];
  const float* Wqkv = (const float*)d_in[2];
  const float* bqkv = (const float*)d_in[3];
  const float* Wvw  = (const float*)d_in[4];
  const float* bvw  = (const float*)d_in[5];
  const float* g1   = (const float*)d_in[6];
  const float* b1   = (const float*)d_in[7];
  const float* WA   = (const float*)d_in[8];
  const float* bA   = (const float*)d_in[9];
  const float* WB   = (const float*)d_in[10];
  const float* bB   = (const float*)d_in[11];
  const float* g2   = (const float*)d_in[12];
  const float* b2   = (const float*)d_in[13];
  float* out = (float*)d_out;

  if (ws_size < 100663296) return;
  char* ws = (char*)d_ws;
  u16*  WqkvT = (u16*)(ws + 0);          // [3072][1024] bf16 (dead after QKV)
  u16*  WvwT  = (u16*)(ws + 6291456);    // [1024][1024]
  u16*  WAT   = (u16*)(ws + 8388608);    // [4096][1024]
  u16*  WBT   = (u16*)(ws + 16777216);   // [1024][4096]
  u16*  xb    = (u16*)(ws + 25165824);   // [4096][1024] bf16
  u16*  qkvb  = (u16*)(ws + 33554432);   // [4096][3072] bf16
  u16*  vwb   = (u16*)(ws + 58720256);   // [4096][1024] bf16
  float* a    = (float*)(ws + 67108864); // [4096][1024] f32
  float* nf   = (float*)(ws + 83886080); // [4096][1024] f32
  u16*  nb    = (u16*)(ws + 25165824);   // alias xb (dead after QKV)
  u16*  z     = (u16*)(ws + 33554432);   // [4096][4096] bf16, alias qkvb+vwb
  u16*  Vtb   = (u16*)(ws + 67108864);   // [32][64][2048] bf16, alias a
  float* pp   = (float*)ws;              // MLP-B partials (z=0 -> ws[0,16MB), z=1 -> ws[64,80MB))

  hipError_t e2 = hipFuncSetAttribute((const void*)&k_gemm256<true, true>,
                                      hipFuncAttributeMaxDynamicSharedMemorySize, 131072);
  const bool use256 = (e2 == hipSuccess);

  // 1. casts / transposes (one launch for all 4 weight transposes)
  k_f32_to_bf16<<<dim3(NBS * ND / 4 / 256), 256, 0, stream>>>(x, xb, NBS * ND / 4);
  k_transpose_all<<<dim3(12288), 256, 0, stream>>>(Wqkv, Wvw, WA, WB, WqkvT, WvwT, WAT, WBT);

  // 2. qkv = x @ Wqkv + bqkv -> bf16 [4096][3072]
  k_gemm_bt<true, false><<<dim3(3 * ND / 128, NBS / 128, 1), 256, 0, stream>>>(
      xb, WqkvT, bqkv, qkvb, NBS, 3 * ND, ND, ND, 0);

  // 3. V transpose, then flash attention (QBLK=128, 8 waves, paired KV tiles)
  k_vt<<<dim3(NS / 64, NB * NH), 256, 0, stream>>>(qkvb, Vtb);
  k_flash_attn<<<dim3(NS / 128, NB * NH), 512, 0, stream>>>(qkvb, Vtb, vwb);

  // 4. a = vw @ Wvw + bvw -> f32
  k_gemm_bt<false, false><<<dim3(ND / 128, NBS / 128, 1), 256, 0, stream>>>(
      vwb, WvwT, bvw, a, NBS, ND, ND, ND, 0);

  // 5. n = LN(x + a) -> nf (f32) + nb (bf16)
  k_add_ln<true><<<dim3(NBS), 256, 0, stream>>>(x, a, g1, b1, nf, nb);

  // 6. z = relu(n @ WA + bA) -> bf16 [4096][4096]
  if (use256)
    k_gemm256<true, true><<<dim3((4 * ND / 256) * (NBS / 256)), 512, 131072, stream>>>(
        nb, WAT, bA, z, NBS, 4 * ND, ND, 4 * ND / 256);
  else
    k_gemm_bt<true, true><<<dim3(4 * ND / 128, NBS / 128, 1), 256, 0, stream>>>(
        nb, WAT, bA, z, NBS, 4 * ND, ND, ND, 0);

  // 7. m = z @ WB (split-K=2 partials, no bias) -> pp[0], pp[1]
  k_gemm_bt<false, false><<<dim3(ND / 128, NBS / 128, 2), 256, 0, stream>>>(
      z, WBT, nullptr, pp, NBS, ND, 4 * ND, 2 * ND, (size_t)16777216);

  // 8. h = LN(nf + p0 + p1 + bB) -> d_out
  k_add_ln2<<<dim3(NBS), 256, 0, stream>>>(nf, pp, pp + 16777216, bB, g2, b2, out);
}